// Round 2
// baseline (892.592 us; speedup 1.0000x reference)
//
#include <hip/hip_runtime.h>

// GCN 2-layer + pool + head, via edge binning:
//   bin edges by col>>6 (64-node buckets) -> all scatter-adds become LDS accumulations.
// Eliminates all random global atomics (R1 evidence: 3.2M random-line atomic RMWs = 163us each,
// write-through to HBM at 32B/atomic).

#define SH 6                 // log2 nodes per bucket
#define RB 64                // nodes per bucket
#define KMAX 2048            // max buckets (N <= 131072; also row packs in 17 bits)
#define TPB 256

// ---------- binning ----------

__global__ void k_count(const int* __restrict__ col, unsigned* __restrict__ bucketCount,
                        int E, int K) {
    __shared__ unsigned lh[KMAX];
    for (int i = threadIdx.x; i < K; i += blockDim.x) lh[i] = 0u;
    __syncthreads();
    for (long long e = (long long)blockIdx.x * blockDim.x + threadIdx.x; e < E;
         e += (long long)gridDim.x * blockDim.x)
        atomicAdd(&lh[col[e] >> SH], 1u);
    __syncthreads();
    for (int i = threadIdx.x; i < K; i += blockDim.x)
        if (lh[i]) atomicAdd(&bucketCount[i], lh[i]);
}

__global__ void k_scan(const unsigned* __restrict__ cnt, unsigned* __restrict__ start,
                       unsigned* __restrict__ cursor, int K) {
    __shared__ unsigned a[KMAX], b[KMAX];
    int t = threadIdx.x;  // 1024
    for (int i = t; i < KMAX; i += 1024) a[i] = (i < K) ? cnt[i] : 0u;
    __syncthreads();
    unsigned *src = a, *dst = b;
    for (int off = 1; off < KMAX; off <<= 1) {
        for (int i = t; i < KMAX; i += 1024)
            dst[i] = (i >= off) ? src[i] + src[i - off] : src[i];
        __syncthreads();
        unsigned* tmp = src; src = dst; dst = tmp;
    }
    for (int i = t; i < K; i += 1024) {
        unsigned ex = (i == 0) ? 0u : src[i - 1];
        start[i] = ex; cursor[i] = ex;
    }
}

__global__ void k_binscatter(const int* __restrict__ row, const int* __restrict__ col,
                             const float* __restrict__ w, unsigned* __restrict__ cursor,
                             uint2* __restrict__ brcw, int E, int K) {
    __shared__ unsigned lh[KMAX], lb[KMAX];
    int T = blockDim.x;
    int tile = (E + gridDim.x - 1) / gridDim.x;
    int e0 = blockIdx.x * tile, e1 = min(e0 + tile, E);
    for (int i = threadIdx.x; i < K; i += T) lh[i] = 0u;
    __syncthreads();
    for (int e = e0 + threadIdx.x; e < e1; e += T) atomicAdd(&lh[col[e] >> SH], 1u);
    __syncthreads();
    for (int i = threadIdx.x; i < K; i += T) {
        unsigned c = lh[i];
        lb[i] = c ? atomicAdd(&cursor[i], c) : 0u;
    }
    __syncthreads();
    for (int i = threadIdx.x; i < K; i += T) lh[i] = 0u;
    __syncthreads();
    for (int e = e0 + threadIdx.x; e < e1; e += T) {
        int c = col[e];
        int k = c >> SH;
        unsigned r = atomicAdd(&lh[k], 1u);
        unsigned pos = lb[k] + r;
        brcw[pos] = make_uint2((unsigned)row[e] | ((unsigned)(c & (RB - 1)) << 17),
                               __float_as_uint(w[e]));
    }
}

// ---------- per-bucket deg/dinv ----------

__global__ void k_degdinv(const uint2* __restrict__ brcw, const unsigned* __restrict__ bst,
                          const unsigned* __restrict__ bcnt, float* __restrict__ dinv, int N) {
    int k = blockIdx.x;
    int node0 = k << SH;
    __shared__ float dacc[RB];
    if (threadIdx.x < RB) dacc[threadIdx.x] = 1.0f;  // self-loop weight
    __syncthreads();
    unsigned s = bst[k], c = bcnt[k];
    for (unsigned j = threadIdx.x; j < c; j += blockDim.x) {
        uint2 p = brcw[s + j];
        atomicAdd(&dacc[p.x >> 17], __uint_as_float(p.y));
    }
    __syncthreads();
    int i = threadIdx.x;
    if (i < RB && node0 + i < N) dinv[node0 + i] = rsqrtf(dacc[i]);
}

// ---------- dense per-node transforms ----------

__global__ void k_l1init(const float* __restrict__ x, const float* __restrict__ W1,
                         float* __restrict__ hx, int N) {
    int t = blockIdx.x * blockDim.x + threadIdx.x;
    int i = t >> 4, f = t & 15;
    if (i >= N) return;
    float x0 = x[i * 3 + 0], x1 = x[i * 3 + 1], x2 = x[i * 3 + 2];
    hx[i * 16 + f] = x0 * W1[0 * 16 + f] + x1 * W1[1 * 16 + f] + x2 * W1[2 * 16 + f];
}

__global__ void k_l2init(const float* __restrict__ h1, const float* __restrict__ W2,
                         float* __restrict__ hx2, int N) {
    int t = blockIdx.x * blockDim.x + threadIdx.x;
    int i = t >> 4, f = t & 15;
    if (i >= N) return;
    float v = 0.0f;
#pragma unroll
    for (int kk = 0; kk < 16; kk++) {
        float hk = h1[i * 16 + kk];
        hk = hk > 0.0f ? hk : 0.0f;
        v += hk * W2[kk * 16 + f];
    }
    hx2[i * 16 + f] = v;
}

// ---------- per-bucket conv layer (LDS accumulate) ----------

template <bool WRITE_NORM>
__global__ void k_layer(uint2* __restrict__ brcw, const unsigned* __restrict__ bst,
                        const unsigned* __restrict__ bcnt, const float* __restrict__ dinv,
                        const float* __restrict__ hx, const float* __restrict__ bias,
                        float* __restrict__ hout, int N) {
    int k = blockIdx.x;
    int node0 = k << SH;
    __shared__ float hacc[RB * 16];  // 4KB
    __shared__ float dl[RB];
    int tid = threadIdx.x;
    if (tid < RB) {
        int n = node0 + tid;
        dl[tid] = (n < N) ? dinv[n] : 0.0f;
    }
    __syncthreads();
    int nn = min(RB, N - node0);
    for (int idx = tid; idx < nn * 16; idx += blockDim.x) {
        int i = idx >> 4, f = idx & 15;
        float d = dl[i];
        hacc[idx] = bias[f] + d * d * hx[(node0 + i) * 16 + f];  // self-loop term
    }
    __syncthreads();
    unsigned s = bst[k], c = bcnt[k];
    int f = tid & 15;
    for (unsigned j = (unsigned)(tid >> 4); j < c; j += (blockDim.x >> 4)) {
        uint2 p = brcw[s + j];
        unsigned rw = p.x & 0x1FFFFu;
        unsigned lc = p.x >> 17;
        float nw;
        if (WRITE_NORM) {
            nw = dinv[rw] * __uint_as_float(p.y) * dl[lc];
            if (f == 0) ((float*)(brcw + (s + j)))[1] = nw;  // cache norm for layer 2
        } else {
            nw = __uint_as_float(p.y);
        }
        atomicAdd(&hacc[lc * 16 + f], nw * hx[rw * 16 + f]);
    }
    __syncthreads();
    for (int idx = tid; idx < nn * 16; idx += blockDim.x)
        hout[(node0 + (idx >> 4)) * 16 + (idx & 15)] = hacc[idx];
}

// ---------- pool (sorted batch -> LDS accumulate) ----------

#define PC 1024
__global__ void k_pool(const float* __restrict__ h2, const int* __restrict__ batch,
                       float* __restrict__ pooled, int N, int G) {
    int b0 = blockIdx.x * PC;
    int nodes = min(PC, N - b0);
    __shared__ float lacc[64 * 16];
    __shared__ int lbat[PC];
    int tid = threadIdx.x;  // 256
    for (int i = tid; i < nodes; i += 256) lbat[i] = batch[b0 + i];
    __syncthreads();
    int gmin = lbat[0], gmax = lbat[nodes - 1];
    if (gmax - gmin < 64) {
        for (int i = tid; i < 64 * 16; i += 256) lacc[i] = 0.0f;
        __syncthreads();
        for (int idx = tid; idx < nodes * 16; idx += 256) {
            int i = idx >> 4, f = idx & 15;
            float v = h2[(b0 + i) * 16 + f];
            v = v > 0.0f ? v : 0.0f;
            atomicAdd(&lacc[(lbat[i] - gmin) * 16 + f], v);
        }
        __syncthreads();
        for (int idx = tid; idx < 64 * 16; idx += 256) {
            int g = gmin + (idx >> 4);
            float v = lacc[idx];
            if (g < G && v != 0.0f) atomicAdd(&pooled[g * 16 + (idx & 15)], v);
        }
    } else {  // pathological batch layout fallback
        for (int idx = tid; idx < nodes * 16; idx += 256) {
            int i = idx >> 4, f = idx & 15;
            float v = h2[(b0 + i) * 16 + f];
            v = v > 0.0f ? v : 0.0f;
            atomicAdd(&pooled[lbat[i] * 16 + f], v);
        }
    }
}

__global__ void k_final(const float* __restrict__ pooled, const float* __restrict__ Wlin,
                        const float* __restrict__ blin, float* __restrict__ out, int G) {
    int t = blockIdx.x * blockDim.x + threadIdx.x;
    int g = t / 7, j = t % 7;
    if (g >= G) return;
    float v = blin[j];
#pragma unroll
    for (int f = 0; f < 16; f++) v += pooled[g * 16 + f] * Wlin[f * 7 + j];
    out[g * 7 + j] = v;
}

static inline int cdiv_i(long long a, long long b) { return (int)((a + b - 1) / b); }

extern "C" void kernel_launch(void* const* d_in, const int* in_sizes, int n_in,
                              void* d_out, int out_size, void* d_ws, size_t ws_size,
                              hipStream_t stream) {
    const float* x     = (const float*)d_in[0];
    const int*   ei    = (const int*)d_in[1];
    const float* ew    = (const float*)d_in[2];
    const int*   batch = (const int*)d_in[3];
    const float* W1    = (const float*)d_in[4];
    const float* b1    = (const float*)d_in[5];
    const float* W2    = (const float*)d_in[6];
    const float* b2    = (const float*)d_in[7];
    const float* Wlin  = (const float*)d_in[8];
    const float* blin  = (const float*)d_in[9];
    float* out = (float*)d_out;

    const int N = in_sizes[0] / 3;
    const int E = in_sizes[2];
    const int G = out_size / 7;
    const int K = (N + RB - 1) >> SH;  // 1563 for N=100000
    const int* row = ei;
    const int* col = ei + E;

    // workspace layout (brcw first for 8B alignment)
    uint2*    brcw   = (uint2*)d_ws;                       // E * 8B
    unsigned* bcnt   = (unsigned*)(brcw + E);              // K
    unsigned* bst    = bcnt + KMAX;                        // K
    unsigned* bcur   = bst + KMAX;                         // K
    float*    dinv   = (float*)(bcur + KMAX);              // N
    float*    hx     = dinv + N;                           // N*16 (x@W1, then relu(h1)@W2)
    float*    h1     = hx + (size_t)N * 16;                // N*16 (h1, then h2 reuses it)
    float*    pooled = h1 + (size_t)N * 16;                // G*16

    hipMemsetAsync(bcnt, 0, KMAX * sizeof(unsigned), stream);
    hipMemsetAsync(pooled, 0, (size_t)G * 16 * sizeof(float), stream);

    // bin edges by col>>6
    k_count<<<256, TPB, 0, stream>>>(col, bcnt, E, K);
    k_scan<<<1, 1024, 0, stream>>>(bcnt, bst, bcur, K);
    k_binscatter<<<256, TPB, 0, stream>>>(row, col, ew, bcur, brcw, E, K);

    // deg -> dinv
    k_degdinv<<<K, TPB, 0, stream>>>(brcw, bst, bcnt, dinv, N);

    // layer 1: hx = x@W1; h1 = b1 + dinv^2*hx + scatter(norm*hx[row])   (norm computed+stored)
    k_l1init<<<cdiv_i((long long)N * 16, TPB), TPB, 0, stream>>>(x, W1, hx, N);
    k_layer<true><<<K, TPB, 0, stream>>>(brcw, bst, bcnt, dinv, hx, b1, h1, N);

    // layer 2: hx2 = relu(h1)@W2; h2 = b2 + dinv^2*hx2 + scatter(norm*hx2[row])
    k_l2init<<<cdiv_i((long long)N * 16, TPB), TPB, 0, stream>>>(h1, W2, hx, N);
    k_layer<false><<<K, TPB, 0, stream>>>(brcw, bst, bcnt, dinv, hx, b2, h1, N);

    // pool (relu folded) + head
    k_pool<<<cdiv_i(N, PC), TPB, 0, stream>>>(h1, batch, pooled, N, G);
    k_final<<<cdiv_i((long long)G * 7, TPB), TPB, 0, stream>>>(pooled, Wlin, blin, out, G);
}

// Round 3
// 875.233 us; speedup vs baseline: 1.0198x; 1.0198x over previous
//
#include <hip/hip_runtime.h>

// GCN 2-layer + pool + head via col-binned edges (64-node buckets -> LDS accumulation).
// R3: fix the latency-bound gather in k_layer (R2: 335us, 1 line/114cyc/CU) by
//   (a) splitting each bucket over S blocks (partial sums, no global atomics),
//   (b) 4x unrolled independent gathers (16 random lines in flight per wave),
//   (c) norm precomputed into the binned payload (k_prenorm; dinv is L2-resident).

#define SH 6                 // log2 nodes per bucket
#define RB 64                // nodes per bucket
#define KMAX 2048            // max buckets (N <= 131072: row packs in 17 bits)
#define TPB 256

// ---------- binning ----------

__global__ void k_count(const int* __restrict__ col, unsigned* __restrict__ bucketCount,
                        int E, int K) {
    __shared__ unsigned lh[KMAX];
    for (int i = threadIdx.x; i < K; i += blockDim.x) lh[i] = 0u;
    __syncthreads();
    for (long long e = (long long)blockIdx.x * blockDim.x + threadIdx.x; e < E;
         e += (long long)gridDim.x * blockDim.x)
        atomicAdd(&lh[col[e] >> SH], 1u);
    __syncthreads();
    for (int i = threadIdx.x; i < K; i += blockDim.x)
        if (lh[i]) atomicAdd(&bucketCount[i], lh[i]);
}

__global__ void k_scan(const unsigned* __restrict__ cnt, unsigned* __restrict__ start,
                       unsigned* __restrict__ cursor, int K) {
    __shared__ unsigned a[KMAX], b[KMAX];
    int t = threadIdx.x;  // 1024
    for (int i = t; i < KMAX; i += 1024) a[i] = (i < K) ? cnt[i] : 0u;
    __syncthreads();
    unsigned *src = a, *dst = b;
    for (int off = 1; off < KMAX; off <<= 1) {
        for (int i = t; i < KMAX; i += 1024)
            dst[i] = (i >= off) ? src[i] + src[i - off] : src[i];
        __syncthreads();
        unsigned* tmp = src; src = dst; dst = tmp;
    }
    for (int i = t; i < K; i += 1024) {
        unsigned ex = (i == 0) ? 0u : src[i - 1];
        start[i] = ex; cursor[i] = ex;
    }
}

__global__ void k_binscatter(const int* __restrict__ row, const int* __restrict__ col,
                             const float* __restrict__ w, unsigned* __restrict__ cursor,
                             uint2* __restrict__ brcw, int E, int K) {
    __shared__ unsigned lh[KMAX], lb[KMAX];
    int T = blockDim.x;
    int tile = (E + gridDim.x - 1) / gridDim.x;
    int e0 = blockIdx.x * tile, e1 = min(e0 + tile, E);
    for (int i = threadIdx.x; i < K; i += T) lh[i] = 0u;
    __syncthreads();
    for (int e = e0 + threadIdx.x; e < e1; e += T) atomicAdd(&lh[col[e] >> SH], 1u);
    __syncthreads();
    for (int i = threadIdx.x; i < K; i += T) {
        unsigned c = lh[i];
        lb[i] = c ? atomicAdd(&cursor[i], c) : 0u;
    }
    __syncthreads();
    for (int i = threadIdx.x; i < K; i += T) lh[i] = 0u;
    __syncthreads();
    for (int e = e0 + threadIdx.x; e < e1; e += T) {
        int c = col[e];
        int k = c >> SH;
        unsigned r = atomicAdd(&lh[k], 1u);
        unsigned pos = lb[k] + r;
        brcw[pos] = make_uint2((unsigned)row[e] | ((unsigned)(c & (RB - 1)) << 17),
                               __float_as_uint(w[e]));
    }
}

// ---------- per-bucket deg/dinv ----------

__global__ void k_degdinv(const uint2* __restrict__ brcw, const unsigned* __restrict__ bst,
                          const unsigned* __restrict__ bcnt, float* __restrict__ dinv, int N) {
    int k = blockIdx.x;
    int node0 = k << SH;
    __shared__ float dacc[RB];
    if (threadIdx.x < RB) dacc[threadIdx.x] = 1.0f;  // self-loop weight
    __syncthreads();
    unsigned s = bst[k], c = bcnt[k];
    for (unsigned j = threadIdx.x; j < c; j += blockDim.x) {
        uint2 p = brcw[s + j];
        atomicAdd(&dacc[p.x >> 17], __uint_as_float(p.y));
    }
    __syncthreads();
    int i = threadIdx.x;
    if (i < RB && node0 + i < N) dinv[node0 + i] = rsqrtf(dacc[i]);
}

// replace edge weight with full norm = dinv[row]*w*dinv[col]  (dinv: 400KB, L2-resident)
__global__ void k_prenorm(uint2* __restrict__ brcw, const unsigned* __restrict__ bst,
                          const unsigned* __restrict__ bcnt, const float* __restrict__ dinv,
                          int N) {
    int k = blockIdx.x;
    int node0 = k << SH;
    __shared__ float dl[RB];
    if (threadIdx.x < RB) {
        int n = node0 + threadIdx.x;
        dl[threadIdx.x] = (n < N) ? dinv[n] : 0.0f;
    }
    __syncthreads();
    unsigned s = bst[k], c = bcnt[k];
    for (unsigned j = threadIdx.x; j < c; j += blockDim.x) {
        uint2 p = brcw[s + j];
        float nw = dinv[p.x & 0x1FFFFu] * __uint_as_float(p.y) * dl[p.x >> 17];
        brcw[s + j] = make_uint2(p.x, __float_as_uint(nw));
    }
}

// ---------- dense: hx = x @ W1 ----------

__global__ void k_l1init(const float* __restrict__ x, const float* __restrict__ W1,
                         float* __restrict__ hx, int N) {
    int t = blockIdx.x * blockDim.x + threadIdx.x;
    int i = t >> 4, f = t & 15;
    if (i >= N) return;
    float x0 = x[i * 3 + 0], x1 = x[i * 3 + 1], x2 = x[i * 3 + 2];
    hx[i * 16 + f] = x0 * W1[0 * 16 + f] + x1 * W1[1 * 16 + f] + x2 * W1[2 * 16 + f];
}

// ---------- edge scatter: partial per-bucket sums, S splits ----------

__global__ __launch_bounds__(TPB, 8)
void k_layer(const uint2* __restrict__ brcw, const unsigned* __restrict__ bst,
             const unsigned* __restrict__ bcnt, const float* __restrict__ hx,
             float* __restrict__ hpart, int N) {
    int k = blockIdx.x;
    int sp = blockIdx.y, S = gridDim.y;
    int node0 = k << SH;
    __shared__ float hacc[RB * 16];  // 4KB
    int tid = threadIdx.x;
    for (int idx = tid; idx < RB * 16; idx += TPB) hacc[idx] = 0.0f;
    __syncthreads();
    unsigned s = bst[k], c = bcnt[k];
    unsigned cs = (c + S - 1) / S;
    unsigned j0 = (unsigned)sp * cs, j1 = min(j0 + cs, c);
    int f = tid & 15;
    const unsigned step = TPB / 16;  // 16 groups
    unsigned j = j0 + (unsigned)(tid >> 4);
    // 4 independent gathers in flight per group
    for (; j + 3 * step < j1; j += 4 * step) {
        uint2 p0 = brcw[s + j];
        uint2 p1 = brcw[s + j + step];
        uint2 p2 = brcw[s + j + 2 * step];
        uint2 p3 = brcw[s + j + 3 * step];
        float v0 = hx[(p0.x & 0x1FFFFu) * 16 + f];
        float v1 = hx[(p1.x & 0x1FFFFu) * 16 + f];
        float v2 = hx[(p2.x & 0x1FFFFu) * 16 + f];
        float v3 = hx[(p3.x & 0x1FFFFu) * 16 + f];
        atomicAdd(&hacc[(p0.x >> 17) * 16 + f], __uint_as_float(p0.y) * v0);
        atomicAdd(&hacc[(p1.x >> 17) * 16 + f], __uint_as_float(p1.y) * v1);
        atomicAdd(&hacc[(p2.x >> 17) * 16 + f], __uint_as_float(p2.y) * v2);
        atomicAdd(&hacc[(p3.x >> 17) * 16 + f], __uint_as_float(p3.y) * v3);
    }
    for (; j < j1; j += step) {
        uint2 p = brcw[s + j];
        float v = hx[(p.x & 0x1FFFFu) * 16 + f];
        atomicAdd(&hacc[(p.x >> 17) * 16 + f], __uint_as_float(p.y) * v);
    }
    __syncthreads();
    int nn = min(RB, N - node0);
    float* dstp = hpart + (size_t)sp * N * 16;
    for (int idx = tid; idx < nn * 16; idx += TPB)
        dstp[(node0 + (idx >> 4)) * 16 + (idx & 15)] = hacc[idx];
}

// ---------- mid: h1 = relu(b1 + dinv^2*hx + sum hpart); hx <- h1 @ W2 (in-place) ----------

__global__ void k_mid(float* __restrict__ hx, const float* __restrict__ hpart,
                      const float* __restrict__ dinv, const float* __restrict__ b1,
                      const float* __restrict__ W2, int N, int S) {
    __shared__ float t[16][16];
    __shared__ float w2[256];
    int tid = threadIdx.x;
    int il = tid >> 4, f = tid & 15;
    int i = blockIdx.x * 16 + il;
    w2[tid] = W2[tid];
    float v = 0.0f;
    if (i < N) {
        float d = dinv[i];
        v = b1[f] + d * d * hx[i * 16 + f];
        for (int s = 0; s < S; s++) v += hpart[(size_t)s * N * 16 + i * 16 + f];
        v = v > 0.0f ? v : 0.0f;
    }
    t[il][f] = v;
    __syncthreads();
    if (i < N) {
        float o = 0.0f;
#pragma unroll
        for (int kk = 0; kk < 16; kk++) o += t[il][kk] * w2[kk * 16 + f];
        hx[i * 16 + f] = o;
    }
}

// ---------- pool: h2 = relu(b2 + dinv^2*hx2 + sum hpart) folded into batch-pool ----------

#define PC 1024
__global__ void k_pool(const float* __restrict__ hx2, const float* __restrict__ hpart,
                       const float* __restrict__ dinv, const float* __restrict__ b2,
                       const int* __restrict__ batch, float* __restrict__ pooled,
                       int N, int G, int S) {
    int b0 = blockIdx.x * PC;
    int nodes = min(PC, N - b0);
    __shared__ float lacc[64 * 16];
    __shared__ int lbat[PC];
    int tid = threadIdx.x;  // 256
    for (int i = tid; i < nodes; i += 256) lbat[i] = batch[b0 + i];
    __syncthreads();
    int gmin = lbat[0], gmax = lbat[nodes - 1];
    bool fits = (gmax - gmin < 64);
    if (fits) {
        for (int i = tid; i < 64 * 16; i += 256) lacc[i] = 0.0f;
        __syncthreads();
    }
    for (int idx = tid; idx < nodes * 16; idx += 256) {
        int i = idx >> 4, f = idx & 15;
        int n = b0 + i;
        float d = dinv[n];
        float v = b2[f] + d * d * hx2[n * 16 + f];
        for (int s = 0; s < S; s++) v += hpart[(size_t)s * N * 16 + n * 16 + f];
        v = v > 0.0f ? v : 0.0f;
        if (fits) atomicAdd(&lacc[(lbat[i] - gmin) * 16 + f], v);
        else      atomicAdd(&pooled[lbat[i] * 16 + f], v);
    }
    if (fits) {
        __syncthreads();
        for (int idx = tid; idx < 64 * 16; idx += 256) {
            int g = gmin + (idx >> 4);
            float v = lacc[idx];
            if (g < G && v != 0.0f) atomicAdd(&pooled[g * 16 + (idx & 15)], v);
        }
    }
}

__global__ void k_final(const float* __restrict__ pooled, const float* __restrict__ Wlin,
                        const float* __restrict__ blin, float* __restrict__ out, int G) {
    int t = blockIdx.x * blockDim.x + threadIdx.x;
    int g = t / 7, j = t % 7;
    if (g >= G) return;
    float v = blin[j];
#pragma unroll
    for (int f = 0; f < 16; f++) v += pooled[g * 16 + f] * Wlin[f * 7 + j];
    out[g * 7 + j] = v;
}

static inline int cdiv_i(long long a, long long b) { return (int)((a + b - 1) / b); }

extern "C" void kernel_launch(void* const* d_in, const int* in_sizes, int n_in,
                              void* d_out, int out_size, void* d_ws, size_t ws_size,
                              hipStream_t stream) {
    const float* x     = (const float*)d_in[0];
    const int*   ei    = (const int*)d_in[1];
    const float* ew    = (const float*)d_in[2];
    const int*   batch = (const int*)d_in[3];
    const float* W1    = (const float*)d_in[4];
    const float* b1    = (const float*)d_in[5];
    const float* W2    = (const float*)d_in[6];
    const float* b2    = (const float*)d_in[7];
    const float* Wlin  = (const float*)d_in[8];
    const float* blin  = (const float*)d_in[9];
    float* out = (float*)d_out;

    const int N = in_sizes[0] / 3;
    const int E = in_sizes[2];
    const int G = out_size / 7;
    const int K = (N + RB - 1) >> SH;  // 1563 for N=100000
    const int* row = ei;
    const int* col = ei + E;

    // workspace layout (brcw first for 8B alignment)
    uint2*    brcw   = (uint2*)d_ws;                       // E * 8B
    unsigned* bcnt   = (unsigned*)(brcw + E);              // KMAX
    unsigned* bst    = bcnt + KMAX;                        // KMAX
    unsigned* bcur   = bst + KMAX;                         // KMAX
    float*    dinv   = (float*)(bcur + KMAX);              // N
    float*    hx     = dinv + N;                           // N*16 (x@W1 -> h1@W2 in-place)
    float*    pooled = hx + (size_t)N * 16;                // G*16
    float*    hpart  = pooled + (size_t)G * 16;            // S * N*16

    size_t fixed = (char*)hpart - (char*)d_ws;
    size_t per_part = (size_t)N * 16 * sizeof(float);
    int S = (int)((ws_size - fixed) / per_part);
    S = S < 1 ? 1 : (S > 4 ? 4 : S);

    hipMemsetAsync(bcnt, 0, KMAX * sizeof(unsigned), stream);
    hipMemsetAsync(pooled, 0, (size_t)G * 16 * sizeof(float), stream);

    // bin edges by col>>6
    k_count<<<256, TPB, 0, stream>>>(col, bcnt, E, K);
    k_scan<<<1, 1024, 0, stream>>>(bcnt, bst, bcur, K);
    k_binscatter<<<256, TPB, 0, stream>>>(row, col, ew, bcur, brcw, E, K);

    // deg -> dinv; fold norm into binned payload
    k_degdinv<<<K, TPB, 0, stream>>>(brcw, bst, bcnt, dinv, N);
    k_prenorm<<<K, TPB, 0, stream>>>(brcw, bst, bcnt, dinv, N);

    // layer 1
    k_l1init<<<cdiv_i((long long)N * 16, TPB), TPB, 0, stream>>>(x, W1, hx, N);
    k_layer<<<dim3(K, S), TPB, 0, stream>>>(brcw, bst, bcnt, hx, hpart, N);
    k_mid<<<cdiv_i(N, 16), TPB, 0, stream>>>(hx, hpart, dinv, b1, W2, N, S);

    // layer 2
    k_layer<<<dim3(K, S), TPB, 0, stream>>>(brcw, bst, bcnt, hx, hpart, N);
    k_pool<<<cdiv_i(N, PC), TPB, 0, stream>>>(hx, hpart, dinv, b2, batch, pooled, N, G, S);

    k_final<<<cdiv_i((long long)G * 7, TPB), TPB, 0, stream>>>(pooled, Wlin, blin, out, G);
}